// Round 19
// baseline (343.060 us; speedup 1.0000x reference)
//
#include <hip/hip_runtime.h>

#define NN 10000
#define NE 320000

typedef __bf16 bf16x8 __attribute__((ext_vector_type(8)));
typedef short  s16x8  __attribute__((ext_vector_type(8)));
typedef float  f32x4  __attribute__((ext_vector_type(4)));

__device__ __forceinline__ unsigned short f2bf(float f) {
  return __builtin_bit_cast(unsigned short, (__bf16)f);
}
__device__ __forceinline__ float bf2f(unsigned short s) {
  unsigned u = ((unsigned)s) << 16;
  return __builtin_bit_cast(float, u);
}
__device__ __forceinline__ float sigm(float x) {
  return __builtin_amdgcn_rcpf(1.0f + __expf(-x));
}
__device__ __forceinline__ float silu_f(float x) {
  return x * __builtin_amdgcn_rcpf(1.0f + __expf(-x));
}

// ---------------- prep_all: {weight transpose | h->bf16 | row hist} fused -------
// 512 threads. blocks [0,784): weights ; [784,2034): h ; [2034,2659): hist
__global__ __launch_bounds__(512) void prep_all(
    const float* __restrict__ We1, const float* __restrict__ We2,
    const float* __restrict__ Wn1, const float* __restrict__ Wn2,
    const float* __restrict__ h, const int* __restrict__ eidx,
    unsigned short* __restrict__ W1abT, unsigned short* __restrict__ W1cT,
    unsigned short* __restrict__ We2T,
    unsigned short* __restrict__ Wn1T, unsigned short* __restrict__ Wn2T,
    unsigned short* __restrict__ hb, int* __restrict__ rowi, int* __restrict__ counts) {
  const int b = blockIdx.x;
  if (b < 784) {
    int g = b * 512 + threadIdx.x;
    const int S1 = 512 * 256, S2 = 256 * 32, S3 = 256 * 256, S4 = 256 * 512, S5 = 256 * 256;
    if (g < S1) {
      int n = g >> 8, k = g & 255;
      float v = (n < 256) ? We1[k * 256 + n] : We1[(256 + k) * 256 + (n - 256)];
      W1abT[g] = f2bf(v);
    } else if (g < S1 + S2) {
      int i = g - S1; int n = i >> 5, kk = i & 31;
      float v = (kk < 16) ? We1[(512 + kk) * 256 + n] : 0.0f;
      W1cT[i] = f2bf(v);
    } else if (g < S1 + S2 + S3) {
      int i = g - S1 - S2; int n = i >> 8, k = i & 255;
      We2T[i] = f2bf(We2[k * 256 + n]);
    } else if (g < S1 + S2 + S3 + S4) {
      int i = g - S1 - S2 - S3; int n = i >> 9, k = i & 511;
      Wn1T[i] = f2bf(Wn1[k * 256 + n]);
    } else if (g < S1 + S2 + S3 + S4 + S5) {
      int i = g - S1 - S2 - S3 - S4; int n = i >> 8, k = i & 255;
      Wn2T[i] = f2bf(Wn2[k * 256 + n]);
    }
  } else if (b < 2034) {
    int g = (b - 784) * 512 + threadIdx.x;    // < NN*64 = 640000 exactly
    float4 f = ((const float4*)h)[g];
    unsigned short* d = hb + g * 4;
    d[0] = f2bf(f.x); d[1] = f2bf(f.y); d[2] = f2bf(f.z); d[3] = f2bf(f.w);
  } else {
    __shared__ int s64;
    if (threadIdx.x == 0) {
      bool bb = true;
      for (int i = 1; i < 64; i += 2) bb = bb && (eidx[i] == 0);
      s64 = bb ? 1 : 0;
    }
    __syncthreads();
    int e = (b - 2034) * 512 + threadIdx.x;   // < NE = 320000 exactly
    int r = s64 ? (int)((const long long*)eidx)[e] : eidx[e];
    rowi[e] = r;
    atomicAdd(&counts[r], 1);
  }
}

// ---------------- CSR scan ------------------------------------------------------
__global__ __launch_bounds__(1024) void scan_kernel(const int* __restrict__ counts,
                                                    int* __restrict__ rowStart,
                                                    int* __restrict__ cursor) {
  __shared__ int part[1024];
  int t = threadIdx.x;
  int local[10];
  int s = 0;
  #pragma unroll
  for (int i = 0; i < 10; i++) {
    int idx = t * 10 + i;
    int c = (idx < NN) ? counts[idx] : 0;
    local[i] = s; s += c;
  }
  part[t] = s;
  __syncthreads();
  int val = s;
  for (int off = 1; off < 1024; off <<= 1) {
    int tmp = (t >= off) ? part[t - off] : 0;
    __syncthreads();
    part[t] += tmp;
    __syncthreads();
  }
  int base = part[t] - val;
  #pragma unroll
  for (int i = 0; i < 10; i++) {
    int idx = t * 10 + i;
    if (idx < NN) { int v = base + local[i]; rowStart[idx] = v; cursor[idx] = v; }
  }
  if (t == 1023) rowStart[NN] = NE;
}

// ---------------- hpq_scatter: {hPQ GEMM | CSR scatter} fused -------------------
// 512 threads. blocks [0,158): hpq (coh = b&1, n0 = (b>>1)*128) ; [158,783): scatter
__global__ __launch_bounds__(512) void hpq_scatter(
    const unsigned short* __restrict__ hb, const unsigned short* __restrict__ W1abT,
    unsigned short* __restrict__ hPQb,
    const int* __restrict__ rowi, int* __restrict__ cursor,
    int* __restrict__ eorder, int* __restrict__ rowSorted) {
  const int b = blockIdx.x;
  if (b >= 158) {
    int e = (b - 158) * 512 + threadIdx.x;    // < NE = 320000 exactly
    int r = rowi[e];
    int pos = atomicAdd(&cursor[r], 1);
    eorder[pos] = e;
    rowSorted[pos] = r;
    return;
  }

  __shared__ unsigned short Abuf[128 * 40];

  const int tid = threadIdx.x;
  const int lane = tid & 63;
  const int wid = tid >> 6;
  const int wrr = wid >> 2, wcc = wid & 3;
  const int n0 = (b >> 1) * 128;
  const int coh = b & 1;
  const unsigned short* Bsrc = W1abT + ((size_t)(coh << 8)) * 256;

  f32x4 acc[4][4];
  #pragma unroll
  for (int m = 0; m < 4; m++)
    #pragma unroll
    for (int n = 0; n < 4; n++) acc[m][n] = (f32x4){0.f, 0.f, 0.f, 0.f};

  const int eA = tid >> 2, sA = tid & 3;
  int nodeA = n0 + eA; if (nodeA >= NN) nodeA = NN - 1;
  const int rbase = (wrr << 6) + (lane & 15);
  const int koff = (lane >> 4) << 3;
  const int cfrag = lane & 15;

  for (int kt = 0; kt < 8; ++kt) {
    const int k0 = kt << 5;
    __syncthreads();
    *(s16x8*)&Abuf[eA * 40 + (sA << 3)] = *(const s16x8*)(hb + (size_t)nodeA * 256 + k0 + (sA << 3));
    __syncthreads();
    bf16x8 a[4], bb[4];
    #pragma unroll
    for (int m = 0; m < 4; m++)
      a[m] = __builtin_bit_cast(bf16x8, *(const s16x8*)&Abuf[(rbase + m * 16) * 40 + koff]);
    #pragma unroll
    for (int n = 0; n < 4; n++)
      bb[n] = __builtin_bit_cast(bf16x8,
               *(const s16x8*)(Bsrc + (((wcc << 6) + n * 16 + cfrag) << 8) + k0 + koff));
    #pragma unroll
    for (int m = 0; m < 4; m++)
      #pragma unroll
      for (int n = 0; n < 4; n++)
        acc[m][n] = __builtin_amdgcn_mfma_f32_16x16x32_bf16(a[m], bb[n], acc[m][n], 0, 0, 0);
  }

  #pragma unroll
  for (int m = 0; m < 4; m++) {
    int rl = (wrr << 6) + m * 16 + ((lane >> 4) << 2);
    #pragma unroll
    for (int n = 0; n < 4; n++) {
      int cg = (wcc << 6) + n * 16 + cfrag;
      #pragma unroll
      for (int j = 0; j < 4; j++) {
        int rg = n0 + rl + j;
        if (rg < NN) hPQb[(size_t)rg * 512 + (coh << 8) + cg] = f2bf(acc[m][n][j]);
      }
    }
  }
}

// ---------------- edge kernel: r15 base + coalesced post-pass mij burst ---------
__global__ __launch_bounds__(512, 4) void edge_kernel(
    const unsigned short* __restrict__ hPQb, const int* __restrict__ eidx,
    const float* __restrict__ eattr, const float* __restrict__ emask,
    const unsigned short* __restrict__ W1cT, const float* __restrict__ be1,
    const unsigned short* __restrict__ We2T, const float* __restrict__ be2,
    const float* __restrict__ Wa, const float* __restrict__ ba,
    const int* __restrict__ eorder, const int* __restrict__ rowSorted,
    float* __restrict__ mij_out, float* __restrict__ agg) {
  __shared__ unsigned short A2[128 * 264];         // 67584 B: SUM -> hidden1 -> mij bf16
  __shared__ float attP[4][128];
  __shared__ float attL[128];
  __shared__ int rowL[128], colL[128], origL[128];
  __shared__ float waL[256], be1L[256], be2L[256];
  __shared__ int s64;

  const int tid = threadIdx.x;
  const int lane = tid & 63;
  const int wid = tid >> 6;
  const int wr = wid >> 2, wc = wid & 3;
  // bijective XCD swizzle (m204): nwg=2500 = 8*312 + 4
  const int nwg = NE / 128, q = nwg >> 3, r = nwg & 7;
  const int xcd = blockIdx.x & 7, bi = blockIdx.x >> 3;
  const int wg = (xcd < r ? xcd * (q + 1) : r * (q + 1) + (xcd - r) * q) + bi;
  const int e0 = wg * 128;
  const int cfrag = lane & 15;
  const int lq = lane >> 4;
  const int koff = lq << 3;
  const int rbase = (wr << 6) + cfrag;

  if (tid == 0) {
    bool b = true;
    for (int i = 1; i < 64; i += 2) b = b && (eidx[i] == 0);
    s64 = b ? 1 : 0;
  }
  __syncthreads();

  if (tid < 128) {
    int orig = eorder[e0 + tid];
    origL[tid] = orig;
    rowL[tid] = rowSorted[e0 + tid];
    colL[tid] = s64 ? (int)((const long long*)eidx)[NE + orig] : eidx[NE + orig];
  }
  if (tid >= 256) {
    int i = tid - 256;
    waL[i] = Wa[i]; be1L[i] = be1[i]; be2L[i] = be2[i];
  }
  __syncthreads();  // rowL/colL/origL ready

  f32x4 acc[4][4];
  #pragma unroll
  for (int m = 0; m < 4; m++)
    #pragma unroll
    for (int n = 0; n < 4; n++) acc[m][n] = (f32x4){0.f, 0.f, 0.f, 0.f};

  // ---- phase B: SUM staging -> A2 (4 threads/edge, 64 cols each) + t0 MFMA ----
  {
    int e = tid >> 2, p = tid & 3;
    int c0 = p << 6;
    const unsigned short* pr = hPQb + (size_t)rowL[e] * 512 + c0;
    const unsigned short* pc = hPQb + (size_t)colL[e] * 512 + 256 + c0;
    #pragma unroll
    for (int qq = 0; qq < 8; ++qq) {
      s16x8 vr = *(const s16x8*)(pr + (qq << 3));
      s16x8 vc = *(const s16x8*)(pc + (qq << 3));
      s16x8 vo;
      #pragma unroll
      for (int j = 0; j < 8; ++j)
        vo[j] = (short)f2bf(bf2f((unsigned short)vr[j]) + bf2f((unsigned short)vc[j]));
      *(s16x8*)&A2[e * 264 + c0 + (qq << 3)] = vo;
    }
  }
  {
    bf16x8 a[4], b[4];
    #pragma unroll
    for (int m = 0; m < 4; m++) {
      int rl = rbase + m * 16;
      if (koff < 16) {
        const float* src = eattr + (size_t)origL[rl] * 16 + koff;
        float4 f0 = *(const float4*)src;
        float4 f1 = *(const float4*)(src + 4);
        s16x8 v;
        v[0] = (short)f2bf(f0.x); v[1] = (short)f2bf(f0.y);
        v[2] = (short)f2bf(f0.z); v[3] = (short)f2bf(f0.w);
        v[4] = (short)f2bf(f1.x); v[5] = (short)f2bf(f1.y);
        v[6] = (short)f2bf(f1.z); v[7] = (short)f2bf(f1.w);
        a[m] = __builtin_bit_cast(bf16x8, v);
      } else {
        a[m] = __builtin_bit_cast(bf16x8, (s16x8){0, 0, 0, 0, 0, 0, 0, 0});
      }
    }
    #pragma unroll
    for (int n = 0; n < 4; n++)
      b[n] = __builtin_bit_cast(bf16x8,
               *(const s16x8*)(W1cT + (((wc << 6) + n * 16 + cfrag) << 5) + koff));
    #pragma unroll
    for (int m = 0; m < 4; m++)
      #pragma unroll
      for (int n = 0; n < 4; n++)
        acc[m][n] = __builtin_amdgcn_mfma_f32_16x16x32_bf16(a[m], b[n], acc[m][n], 0, 0, 0);
  }
  __syncthreads();  // SUM in A2 visible

  // ---- phase C: hidden1 = silu(eattr@Wc + SUM + be1) -> A2 in place -----------
  #pragma unroll
  for (int m = 0; m < 4; m++) {
    int rl = (wr << 6) + m * 16 + (lq << 2);
    #pragma unroll
    for (int n = 0; n < 4; n++) {
      int cg = (wc << 6) + n * 16 + cfrag;
      float bias = be1L[cg];
      #pragma unroll
      for (int j = 0; j < 4; j++) {
        float x = acc[m][n][j] + bf2f(A2[(rl + j) * 264 + cg]) + bias;
        A2[(rl + j) * 264 + cg] = f2bf(silu_f(x));
      }
      acc[m][n] = (f32x4){0.f, 0.f, 0.f, 0.f};
    }
  }
  __syncthreads();  // hidden1 visible

  // ---- phase D: layer 2, K=256, NO barriers (A2 read-only, B from L2) ---------
  #pragma unroll
  for (int t = 0; t < 8; ++t) {
    const int k0 = t << 5;
    bf16x8 a[4], b[4];
    #pragma unroll
    for (int m = 0; m < 4; m++)
      a[m] = __builtin_bit_cast(bf16x8, *(const s16x8*)&A2[(rbase + m * 16) * 264 + k0 + koff]);
    #pragma unroll
    for (int n = 0; n < 4; n++)
      b[n] = __builtin_bit_cast(bf16x8,
               *(const s16x8*)(We2T + (((wc << 6) + n * 16 + cfrag) << 8) + k0 + koff));
    #pragma unroll
    for (int m = 0; m < 4; m++)
      #pragma unroll
      for (int n = 0; n < 4; n++)
        acc[m][n] = __builtin_amdgcn_mfma_f32_16x16x32_bf16(a[m], b[n], acc[m][n], 0, 0, 0);
  }
  __syncthreads();  // all A2 reads done before rewrite

  // ---- phase E: A2 <- bf16 mij + att partial dot (no global store here) -------
  float part[4][4];
  #pragma unroll
  for (int m = 0; m < 4; m++)
    #pragma unroll
    for (int j = 0; j < 4; j++) part[m][j] = 0.f;

  #pragma unroll
  for (int m = 0; m < 4; m++) {
    #pragma unroll
    for (int n = 0; n < 4; n++) {
      int cg = (wc << 6) + n * 16 + cfrag;
      float bias = be2L[cg];
      float wav = waL[cg];
      #pragma unroll
      for (int j = 0; j < 4; j++) {
        int row = (wr << 6) + m * 16 + (lq << 2) + j;
        float x = silu_f(acc[m][n][j] + bias);
        A2[row * 264 + cg] = f2bf(x);
        part[m][j] += x * wav;
      }
    }
  }
  #pragma unroll
  for (int m = 0; m < 4; m++)
    #pragma unroll
    for (int j = 0; j < 4; j++) {
      float p = part[m][j];
      p += __shfl_xor(p, 1);
      p += __shfl_xor(p, 2);
      p += __shfl_xor(p, 4);
      p += __shfl_xor(p, 8);
      part[m][j] = p;
    }
  if (cfrag == 0) {
    #pragma unroll
    for (int m = 0; m < 4; m++)
      #pragma unroll
      for (int j = 0; j < 4; j++)
        attP[wc][(wr << 6) + m * 16 + (lq << 2) + j] = part[m][j];
  }
  __syncthreads();  // A2(mij bf16) + attP visible

  // ---- phase F: attL + ROW-CONTIGUOUS nt mij burst from A2 --------------------
  // flat = i*512+tid -> edge e = flat>>5, col-chunk (flat&31)*8; every wave
  // instruction writes fully-contiguous 128B lines (wave-local write-combining).
  if (tid < 128) {
    float s = attP[0][tid] + attP[1][tid] + attP[2][tid] + attP[3][tid] + ba[0];
    attL[tid] = sigm(s) * emask[origL[tid]];
  }
  #pragma unroll
  for (int i = 0; i < 8; ++i) {
    int flat = (i << 9) + tid;
    int e = flat >> 5;
    int c8 = (flat & 31) << 3;
    s16x8 v = *(const s16x8*)&A2[e * 264 + c8];
    f32x4 lo, hi;
    lo[0] = bf2f((unsigned short)v[0]); lo[1] = bf2f((unsigned short)v[1]);
    lo[2] = bf2f((unsigned short)v[2]); lo[3] = bf2f((unsigned short)v[3]);
    hi[0] = bf2f((unsigned short)v[4]); hi[1] = bf2f((unsigned short)v[5]);
    hi[2] = bf2f((unsigned short)v[6]); hi[3] = bf2f((unsigned short)v[7]);
    float* dst = mij_out + (size_t)origL[e] * 256 + c8;
    __builtin_nontemporal_store(lo, (f32x4*)dst);
    __builtin_nontemporal_store(hi, (f32x4*)(dst + 4));
  }
  __syncthreads();  // attL visible (A2 unchanged)

  // ---- phase G: segmented reduce, 2 halves of 64 sorted edges -----------------
  {
    const int half = tid >> 8;
    const int c = tid & 255;
    const int i0 = half << 6, i1 = i0 + 64;
    const int fd = rowL[i0];
    float acc2 = 0.f;
    int prev = fd;
    for (int i = i0; i < i1; ++i) {
      int rr = rowL[i];
      if (rr != prev) {
        if (prev == fd) atomicAdd(&agg[(size_t)prev * 256 + c], acc2);
        else            agg[(size_t)prev * 256 + c] = acc2;   // interior: sole owner
        acc2 = 0.f; prev = rr;
      }
      acc2 += attL[i] * bf2f(A2[i * 264 + c]);
    }
    atomicAdd(&agg[(size_t)prev * 256 + c], acc2);
  }
}

// ---------------- node kernel: BM=64, staged A, barrier-light, nt hout ----------
__global__ __launch_bounds__(512, 4) void node_kernel(
    const float* __restrict__ h, const float* __restrict__ agg,
    const float* __restrict__ nmask,
    const unsigned short* __restrict__ Wn1T, const float* __restrict__ bn1,
    const unsigned short* __restrict__ Wn2T, const float* __restrict__ bn2,
    float* __restrict__ hout) {
  __shared__ unsigned short Abuf[64 * 40];      // 5120 B
  __shared__ unsigned short A2[64 * 264];       // 33792 B
  __shared__ float bn1L[256], bn2L[256];        // 2048 B

  const int tid = threadIdx.x;
  const int lane = tid & 63;
  const int wid = tid >> 6;
  const int n0 = blockIdx.x * 64;

  if (tid < 256) { bn1L[tid] = bn1[tid]; bn2L[tid] = bn2[tid]; }

  f32x4 acc[2][4];
  #pragma unroll
  for (int m = 0; m < 2; m++)
    #pragma unroll
    for (int n = 0; n < 4; n++) acc[m][n] = (f32x4){0.f, 0.f, 0.f, 0.f};

  const int wrr = wid >> 2, wcc = wid & 3;      // 2 x 4 wave grid, wrr covers 32 rows
  const int rbase = (wrr << 5) + (lane & 15);
  const int koff = (lane >> 4) << 3;
  const int cfrag = lane & 15;

  const int eA = tid >> 2, sA = tid & 3;        // eA 0..127 but only eA<64 used
  int nodeA = n0 + (eA & 63); if (nodeA >= NN) nodeA = NN - 1;

  for (int kt = 0; kt < 16; ++kt) {
    const int k0 = kt << 5;
    __syncthreads();
    if (eA < 64) {
      const float* src = (k0 < 256) ? (h + (size_t)nodeA * 256 + k0 + (sA << 3))
                                    : (agg + (size_t)nodeA * 256 + (k0 - 256) + (sA << 3));
      const float sc = (k0 < 256) ? 1.0f : (1.0f / 32.0f);
      float4 f0 = *(const float4*)src;
      float4 f1 = *(const float4*)(src + 4);
      s16x8 v;
      v[0] = (short)f2bf(f0.x * sc); v[1] = (short)f2bf(f0.y * sc);
      v[2] = (short)f2bf(f0.z * sc); v[3] = (short)f2bf(f0.w * sc);
      v[4] = (short)f2bf(f1.x * sc); v[5] = (short)f2bf(f1.y * sc);
      v[6] = (short)f2bf(f1.z * sc); v[7] = (short)f2bf(f1.w * sc);
      *(s16x8*)&Abuf[eA * 40 + (sA << 3)] = v;
    }
    __syncthreads();
    bf16x8 a[2], b[4];
    #pragma unroll
    for (int m = 0; m < 2; m++)
      a[m] = __builtin_bit_cast(bf16x8, *(const s16x8*)&Abuf[(rbase + m * 16) * 40 + koff]);
    #pragma unroll
    for (int n = 0; n < 4; n++)
      b[n] = __builtin_bit_cast(bf16x8,
               *(const s16x8*)(Wn1T + (((wcc << 6) + n * 16 + cfrag) << 9) + k0 + koff));
    #pragma unroll
    for (int m = 0; m < 2; m++)
      #pragma unroll
      for (int n = 0; n < 4; n++)
        acc[m][n] = __builtin_amdgcn_mfma_f32_16x16x32_bf16(a[m], b[n], acc[m][n], 0, 0, 0);
  }

  #pragma unroll
  for (int m = 0; m < 2; m++) {
    int rl = (wrr << 5) + m * 16 + ((lane >> 4) << 2);
    #pragma unroll
    for (int n = 0; n < 4; n++) {
      int cg = (wcc << 6) + n * 16 + cfrag;
      float bias = bn1L[cg];
      #pragma unroll
      for (int j = 0; j < 4; j++) {
        float x = acc[m][n][j] + bias;
        A2[(rl + j) * 264 + cg] = f2bf(silu_f(x));
      }
      acc[m][n] = (f32x4){0.f, 0.f, 0.f, 0.f};
    }
  }
  __syncthreads();  // hidden1 visible

  #pragma unroll
  for (int kt = 0; kt < 8; ++kt) {
    const int k0 = kt << 5;
    bf16x8 a[2], b[4];
    #pragma unroll
    for (int m = 0; m < 2; m++)
      a[m] = __builtin_bit_cast(bf16x8, *(const s16x8*)&A2[(rbase + m * 16) * 264 + k0 + koff]);
    #pragma unroll
    for (int n = 0; n < 4; n++)
      b[n] = __builtin_bit_cast(bf16x8,
               *(const s16x8*)(Wn2T + (((wcc << 6) + n * 16 + cfrag) << 8) + k0 + koff));
    #pragma unroll
    for (int m = 0; m < 2; m++)
      #pragma unroll
      for (int n = 0; n < 4; n++)
        acc[m][n] = __builtin_amdgcn_mfma_f32_16x16x32_bf16(a[m], b[n], acc[m][n], 0, 0, 0);
  }

  #pragma unroll
  for (int m = 0; m < 2; m++) {
    int rl = (wrr << 5) + m * 16 + ((lane >> 4) << 2);
    #pragma unroll
    for (int n = 0; n < 4; n++) {
      int cg = (wcc << 6) + n * 16 + cfrag;
      #pragma unroll
      for (int j = 0; j < 4; j++) {
        int rg = n0 + rl + j;
        if (rg < NN) {
          float val = acc[m][n][j] + bn2L[cg];
          float o = (h[(size_t)rg * 256 + cg] + val) * nmask[rg];
          __builtin_nontemporal_store(o, &hout[(size_t)rg * 256 + cg]);
        }
      }
    }
  }
}

extern "C" void kernel_launch(void* const* d_in, const int* in_sizes, int n_in,
                              void* d_out, int out_size, void* d_ws, size_t ws_size,
                              hipStream_t stream) {
  (void)in_sizes; (void)n_in; (void)out_size; (void)ws_size;
  const float* h     = (const float*)d_in[0];
  const int*   eidx  = (const int*)d_in[1];
  const float* eattr = (const float*)d_in[2];
  const float* nmask = (const float*)d_in[3];
  const float* emask = (const float*)d_in[4];
  const float* We1 = (const float*)d_in[5];
  const float* be1 = (const float*)d_in[6];
  const float* We2 = (const float*)d_in[7];
  const float* be2 = (const float*)d_in[8];
  const float* Wa  = (const float*)d_in[9];
  const float* ba  = (const float*)d_in[10];
  const float* Wn1 = (const float*)d_in[11];
  const float* bn1 = (const float*)d_in[12];
  const float* Wn2 = (const float*)d_in[13];
  const float* bn2 = (const float*)d_in[14];

  char* ws = (char*)d_ws;
  unsigned short* W1abT = (unsigned short*)(ws + 0);         // 262,144 B
  unsigned short* W1cT  = (unsigned short*)(ws + 262144);    // 16,384
  unsigned short* We2T  = (unsigned short*)(ws + 278528);    // 131,072
  unsigned short* Wn1T  = (unsigned short*)(ws + 409600);    // 262,144
  unsigned short* Wn2T  = (unsigned short*)(ws + 671744);    // 131,072
  unsigned short* hPQb  = (unsigned short*)(ws + 802816);    // 10,240,000
  float* agg      = (float*)(ws + 11042816);                 // 10,240,000
  int*   counts   = (int*)(ws + 21282816);                   // 40,000
  int*   rowStart = (int*)(ws + 21322816);                   // 40,008
  int*   cursor   = (int*)(ws + 21362824);                   // 40,000
  int*   eorder   = (int*)(ws + 21402824);                   // 1,280,000
  int*   rowi     = (int*)(ws + 22682824);                   // 1,280,000
  int*   rowSorted= (int*)(ws + 23962824);                   // 1,280,000
  unsigned short* hb = (unsigned short*)(ws + 25242824);     // 5,120,000 -> 30,362,824

  float* hout = (float*)d_out;
  float* mij  = (float*)d_out + (size_t)NN * 256;

  hipMemsetAsync(counts, 0, NN * sizeof(int), stream);
  hipMemsetAsync(agg, 0, (size_t)NN * 256 * sizeof(float), stream);
  prep_all<<<2659, 512, 0, stream>>>(We1, We2, Wn1, Wn2, h, eidx,
                                     W1abT, W1cT, We2T, Wn1T, Wn2T, hb, rowi, counts);
  scan_kernel<<<1, 1024, 0, stream>>>(counts, rowStart, cursor);
  hpq_scatter<<<783, 512, 0, stream>>>(hb, W1abT, hPQb, rowi, cursor, eorder, rowSorted);
  edge_kernel<<<NE / 128, 512, 0, stream>>>(hPQb, eidx, eattr, emask, W1cT, be1, We2T, be2,
                                            Wa, ba, eorder, rowSorted, mij, agg);
  node_kernel<<<(NN + 63) / 64, 512, 0, stream>>>(h, agg, nmask, Wn1T, bn1, Wn2T, bn2, hout);
}

// Round 20
// 329.222 us; speedup vs baseline: 1.0420x; 1.0420x over previous
//
#include <hip/hip_runtime.h>

#define NN 10000
#define NE 320000

typedef __bf16 bf16x8 __attribute__((ext_vector_type(8)));
typedef short  s16x8  __attribute__((ext_vector_type(8)));
typedef float  f32x4  __attribute__((ext_vector_type(4)));

__device__ __forceinline__ unsigned short f2bf(float f) {
  return __builtin_bit_cast(unsigned short, (__bf16)f);
}
__device__ __forceinline__ float bf2f(unsigned short s) {
  unsigned u = ((unsigned)s) << 16;
  return __builtin_bit_cast(float, u);
}
__device__ __forceinline__ float sigm(float x) {
  return __builtin_amdgcn_rcpf(1.0f + __expf(-x));
}
__device__ __forceinline__ float silu_f(float x) {
  return x * __builtin_amdgcn_rcpf(1.0f + __expf(-x));
}

// ---------------- prep_all: {weight transpose | h->bf16 | row hist} fused -------
// 512 threads. blocks [0,784): weights ; [784,2034): h ; [2034,2659): hist
__global__ __launch_bounds__(512) void prep_all(
    const float* __restrict__ We1, const float* __restrict__ We2,
    const float* __restrict__ Wn1, const float* __restrict__ Wn2,
    const float* __restrict__ h, const int* __restrict__ eidx,
    unsigned short* __restrict__ W1abT, unsigned short* __restrict__ W1cT,
    unsigned short* __restrict__ We2T,
    unsigned short* __restrict__ Wn1T, unsigned short* __restrict__ Wn2T,
    unsigned short* __restrict__ hb, int* __restrict__ rowi, int* __restrict__ counts) {
  const int b = blockIdx.x;
  if (b < 784) {
    int g = b * 512 + threadIdx.x;
    const int S1 = 512 * 256, S2 = 256 * 32, S3 = 256 * 256, S4 = 256 * 512, S5 = 256 * 256;
    if (g < S1) {
      int n = g >> 8, k = g & 255;
      float v = (n < 256) ? We1[k * 256 + n] : We1[(256 + k) * 256 + (n - 256)];
      W1abT[g] = f2bf(v);
    } else if (g < S1 + S2) {
      int i = g - S1; int n = i >> 5, kk = i & 31;
      float v = (kk < 16) ? We1[(512 + kk) * 256 + n] : 0.0f;
      W1cT[i] = f2bf(v);
    } else if (g < S1 + S2 + S3) {
      int i = g - S1 - S2; int n = i >> 8, k = i & 255;
      We2T[i] = f2bf(We2[k * 256 + n]);
    } else if (g < S1 + S2 + S3 + S4) {
      int i = g - S1 - S2 - S3; int n = i >> 9, k = i & 511;
      Wn1T[i] = f2bf(Wn1[k * 256 + n]);
    } else if (g < S1 + S2 + S3 + S4 + S5) {
      int i = g - S1 - S2 - S3 - S4; int n = i >> 8, k = i & 255;
      Wn2T[i] = f2bf(Wn2[k * 256 + n]);
    }
  } else if (b < 2034) {
    int g = (b - 784) * 512 + threadIdx.x;    // < NN*64 = 640000 exactly
    float4 f = ((const float4*)h)[g];
    unsigned short* d = hb + g * 4;
    d[0] = f2bf(f.x); d[1] = f2bf(f.y); d[2] = f2bf(f.z); d[3] = f2bf(f.w);
  } else {
    __shared__ int s64;
    if (threadIdx.x == 0) {
      bool bb = true;
      for (int i = 1; i < 64; i += 2) bb = bb && (eidx[i] == 0);
      s64 = bb ? 1 : 0;
    }
    __syncthreads();
    int e = (b - 2034) * 512 + threadIdx.x;   // < NE = 320000 exactly
    int r = s64 ? (int)((const long long*)eidx)[e] : eidx[e];
    rowi[e] = r;
    atomicAdd(&counts[r], 1);
  }
}

// ---------------- CSR scan ------------------------------------------------------
__global__ __launch_bounds__(1024) void scan_kernel(const int* __restrict__ counts,
                                                    int* __restrict__ rowStart,
                                                    int* __restrict__ cursor) {
  __shared__ int part[1024];
  int t = threadIdx.x;
  int local[10];
  int s = 0;
  #pragma unroll
  for (int i = 0; i < 10; i++) {
    int idx = t * 10 + i;
    int c = (idx < NN) ? counts[idx] : 0;
    local[i] = s; s += c;
  }
  part[t] = s;
  __syncthreads();
  int val = s;
  for (int off = 1; off < 1024; off <<= 1) {
    int tmp = (t >= off) ? part[t - off] : 0;
    __syncthreads();
    part[t] += tmp;
    __syncthreads();
  }
  int base = part[t] - val;
  #pragma unroll
  for (int i = 0; i < 10; i++) {
    int idx = t * 10 + i;
    if (idx < NN) { int v = base + local[i]; rowStart[idx] = v; cursor[idx] = v; }
  }
  if (t == 1023) rowStart[NN] = NE;
}

// ---------------- hpq_scatter: {hPQ GEMM | CSR scatter} fused -------------------
// 512 threads. blocks [0,158): hpq (coh = b&1, n0 = (b>>1)*128) ; [158,783): scatter
__global__ __launch_bounds__(512) void hpq_scatter(
    const unsigned short* __restrict__ hb, const unsigned short* __restrict__ W1abT,
    unsigned short* __restrict__ hPQb,
    const int* __restrict__ rowi, int* __restrict__ cursor,
    int* __restrict__ eorder, int* __restrict__ rowSorted) {
  const int b = blockIdx.x;
  if (b >= 158) {
    int e = (b - 158) * 512 + threadIdx.x;    // < NE = 320000 exactly
    int r = rowi[e];
    int pos = atomicAdd(&cursor[r], 1);
    eorder[pos] = e;
    rowSorted[pos] = r;
    return;
  }

  __shared__ unsigned short Abuf[128 * 40];

  const int tid = threadIdx.x;
  const int lane = tid & 63;
  const int wid = tid >> 6;
  const int wrr = wid >> 2, wcc = wid & 3;
  const int n0 = (b >> 1) * 128;
  const int coh = b & 1;
  const unsigned short* Bsrc = W1abT + ((size_t)(coh << 8)) * 256;

  f32x4 acc[4][4];
  #pragma unroll
  for (int m = 0; m < 4; m++)
    #pragma unroll
    for (int n = 0; n < 4; n++) acc[m][n] = (f32x4){0.f, 0.f, 0.f, 0.f};

  const int eA = tid >> 2, sA = tid & 3;
  int nodeA = n0 + eA; if (nodeA >= NN) nodeA = NN - 1;
  const int rbase = (wrr << 6) + (lane & 15);
  const int koff = (lane >> 4) << 3;
  const int cfrag = lane & 15;

  for (int kt = 0; kt < 8; ++kt) {
    const int k0 = kt << 5;
    __syncthreads();
    *(s16x8*)&Abuf[eA * 40 + (sA << 3)] = *(const s16x8*)(hb + (size_t)nodeA * 256 + k0 + (sA << 3));
    __syncthreads();
    bf16x8 a[4], bb[4];
    #pragma unroll
    for (int m = 0; m < 4; m++)
      a[m] = __builtin_bit_cast(bf16x8, *(const s16x8*)&Abuf[(rbase + m * 16) * 40 + koff]);
    #pragma unroll
    for (int n = 0; n < 4; n++)
      bb[n] = __builtin_bit_cast(bf16x8,
               *(const s16x8*)(Bsrc + (((wcc << 6) + n * 16 + cfrag) << 8) + k0 + koff));
    #pragma unroll
    for (int m = 0; m < 4; m++)
      #pragma unroll
      for (int n = 0; n < 4; n++)
        acc[m][n] = __builtin_amdgcn_mfma_f32_16x16x32_bf16(a[m], bb[n], acc[m][n], 0, 0, 0);
  }

  #pragma unroll
  for (int m = 0; m < 4; m++) {
    int rl = (wrr << 6) + m * 16 + ((lane >> 4) << 2);
    #pragma unroll
    for (int n = 0; n < 4; n++) {
      int cg = (wcc << 6) + n * 16 + cfrag;
      #pragma unroll
      for (int j = 0; j < 4; j++) {
        int rg = n0 + rl + j;
        if (rg < NN) hPQb[(size_t)rg * 512 + (coh << 8) + cg] = f2bf(acc[m][n][j]);
      }
    }
  }
}

// ---------------- edge kernel: r15-exact (nt mij stores; champion total) --------
__global__ __launch_bounds__(512, 4) void edge_kernel(
    const unsigned short* __restrict__ hPQb, const int* __restrict__ eidx,
    const float* __restrict__ eattr, const float* __restrict__ emask,
    const unsigned short* __restrict__ W1cT, const float* __restrict__ be1,
    const unsigned short* __restrict__ We2T, const float* __restrict__ be2,
    const float* __restrict__ Wa, const float* __restrict__ ba,
    const int* __restrict__ eorder, const int* __restrict__ rowSorted,
    float* __restrict__ mij_out, float* __restrict__ agg) {
  __shared__ unsigned short A2[128 * 264];         // 67584 B: SUM -> hidden1 -> mij bf16
  __shared__ float attP[4][128];
  __shared__ float attL[128];
  __shared__ int rowL[128], colL[128], origL[128];
  __shared__ float waL[256], be1L[256], be2L[256];
  __shared__ int s64;

  const int tid = threadIdx.x;
  const int lane = tid & 63;
  const int wid = tid >> 6;
  const int wr = wid >> 2, wc = wid & 3;
  // bijective XCD swizzle (m204): nwg=2500 = 8*312 + 4
  const int nwg = NE / 128, q = nwg >> 3, r = nwg & 7;
  const int xcd = blockIdx.x & 7, bi = blockIdx.x >> 3;
  const int wg = (xcd < r ? xcd * (q + 1) : r * (q + 1) + (xcd - r) * q) + bi;
  const int e0 = wg * 128;
  const int cfrag = lane & 15;
  const int lq = lane >> 4;
  const int koff = lq << 3;
  const int rbase = (wr << 6) + cfrag;

  if (tid == 0) {
    bool b = true;
    for (int i = 1; i < 64; i += 2) b = b && (eidx[i] == 0);
    s64 = b ? 1 : 0;
  }
  __syncthreads();

  if (tid < 128) {
    int orig = eorder[e0 + tid];
    origL[tid] = orig;
    rowL[tid] = rowSorted[e0 + tid];
    colL[tid] = s64 ? (int)((const long long*)eidx)[NE + orig] : eidx[NE + orig];
  }
  if (tid >= 256) {
    int i = tid - 256;
    waL[i] = Wa[i]; be1L[i] = be1[i]; be2L[i] = be2[i];
  }
  __syncthreads();  // rowL/colL/origL ready

  f32x4 acc[4][4];
  #pragma unroll
  for (int m = 0; m < 4; m++)
    #pragma unroll
    for (int n = 0; n < 4; n++) acc[m][n] = (f32x4){0.f, 0.f, 0.f, 0.f};

  // ---- phase B: SUM staging -> A2 (4 threads/edge, 64 cols each) + t0 MFMA ----
  {
    int e = tid >> 2, p = tid & 3;
    int c0 = p << 6;
    const unsigned short* pr = hPQb + (size_t)rowL[e] * 512 + c0;
    const unsigned short* pc = hPQb + (size_t)colL[e] * 512 + 256 + c0;
    #pragma unroll
    for (int qq = 0; qq < 8; ++qq) {
      s16x8 vr = *(const s16x8*)(pr + (qq << 3));
      s16x8 vc = *(const s16x8*)(pc + (qq << 3));
      s16x8 vo;
      #pragma unroll
      for (int j = 0; j < 8; ++j)
        vo[j] = (short)f2bf(bf2f((unsigned short)vr[j]) + bf2f((unsigned short)vc[j]));
      *(s16x8*)&A2[e * 264 + c0 + (qq << 3)] = vo;
    }
  }
  {
    bf16x8 a[4], b[4];
    #pragma unroll
    for (int m = 0; m < 4; m++) {
      int rl = rbase + m * 16;
      if (koff < 16) {
        const float* src = eattr + (size_t)origL[rl] * 16 + koff;
        float4 f0 = *(const float4*)src;
        float4 f1 = *(const float4*)(src + 4);
        s16x8 v;
        v[0] = (short)f2bf(f0.x); v[1] = (short)f2bf(f0.y);
        v[2] = (short)f2bf(f0.z); v[3] = (short)f2bf(f0.w);
        v[4] = (short)f2bf(f1.x); v[5] = (short)f2bf(f1.y);
        v[6] = (short)f2bf(f1.z); v[7] = (short)f2bf(f1.w);
        a[m] = __builtin_bit_cast(bf16x8, v);
      } else {
        a[m] = __builtin_bit_cast(bf16x8, (s16x8){0, 0, 0, 0, 0, 0, 0, 0});
      }
    }
    #pragma unroll
    for (int n = 0; n < 4; n++)
      b[n] = __builtin_bit_cast(bf16x8,
               *(const s16x8*)(W1cT + (((wc << 6) + n * 16 + cfrag) << 5) + koff));
    #pragma unroll
    for (int m = 0; m < 4; m++)
      #pragma unroll
      for (int n = 0; n < 4; n++)
        acc[m][n] = __builtin_amdgcn_mfma_f32_16x16x32_bf16(a[m], b[n], acc[m][n], 0, 0, 0);
  }
  __syncthreads();  // SUM in A2 visible

  // ---- phase C: hidden1 = silu(eattr@Wc + SUM + be1) -> A2 in place -----------
  #pragma unroll
  for (int m = 0; m < 4; m++) {
    int rl = (wr << 6) + m * 16 + (lq << 2);
    #pragma unroll
    for (int n = 0; n < 4; n++) {
      int cg = (wc << 6) + n * 16 + cfrag;
      float bias = be1L[cg];
      #pragma unroll
      for (int j = 0; j < 4; j++) {
        float x = acc[m][n][j] + bf2f(A2[(rl + j) * 264 + cg]) + bias;
        A2[(rl + j) * 264 + cg] = f2bf(silu_f(x));
      }
      acc[m][n] = (f32x4){0.f, 0.f, 0.f, 0.f};
    }
  }
  __syncthreads();  // hidden1 visible

  // ---- phase D: layer 2, K=256, NO barriers (A2 read-only, B from L2) ---------
  #pragma unroll
  for (int t = 0; t < 8; ++t) {
    const int k0 = t << 5;
    bf16x8 a[4], b[4];
    #pragma unroll
    for (int m = 0; m < 4; m++)
      a[m] = __builtin_bit_cast(bf16x8, *(const s16x8*)&A2[(rbase + m * 16) * 264 + k0 + koff]);
    #pragma unroll
    for (int n = 0; n < 4; n++)
      b[n] = __builtin_bit_cast(bf16x8,
               *(const s16x8*)(We2T + (((wc << 6) + n * 16 + cfrag) << 8) + k0 + koff));
    #pragma unroll
    for (int m = 0; m < 4; m++)
      #pragma unroll
      for (int n = 0; n < 4; n++)
        acc[m][n] = __builtin_amdgcn_mfma_f32_16x16x32_bf16(a[m], b[n], acc[m][n], 0, 0, 0);
  }
  __syncthreads();  // all A2 reads done before rewrite

  // ---- phase E: mij fp32 out (nontemporal) + A2 <- bf16 mij + att partial dot -
  float part[4][4];
  #pragma unroll
  for (int m = 0; m < 4; m++)
    #pragma unroll
    for (int j = 0; j < 4; j++) part[m][j] = 0.f;

  #pragma unroll
  for (int m = 0; m < 4; m++) {
    #pragma unroll
    for (int n = 0; n < 4; n++) {
      int cg = (wc << 6) + n * 16 + cfrag;
      float bias = be2L[cg];
      float wav = waL[cg];
      #pragma unroll
      for (int j = 0; j < 4; j++) {
        int row = (wr << 6) + m * 16 + (lq << 2) + j;
        float x = silu_f(acc[m][n][j] + bias);
        __builtin_nontemporal_store(x, &mij_out[(size_t)origL[row] * 256 + cg]);
        A2[row * 264 + cg] = f2bf(x);
        part[m][j] += x * wav;
      }
    }
  }
  #pragma unroll
  for (int m = 0; m < 4; m++)
    #pragma unroll
    for (int j = 0; j < 4; j++) {
      float p = part[m][j];
      p += __shfl_xor(p, 1);
      p += __shfl_xor(p, 2);
      p += __shfl_xor(p, 4);
      p += __shfl_xor(p, 8);
      part[m][j] = p;
    }
  if (cfrag == 0) {
    #pragma unroll
    for (int m = 0; m < 4; m++)
      #pragma unroll
      for (int j = 0; j < 4; j++)
        attP[wc][(wr << 6) + m * 16 + (lq << 2) + j] = part[m][j];
  }
  __syncthreads();
  if (tid < 128) {
    float s = attP[0][tid] + attP[1][tid] + attP[2][tid] + attP[3][tid] + ba[0];
    attL[tid] = sigm(s) * emask[origL[tid]];
  }
  __syncthreads();

  // ---- phase G: segmented reduce, 2 halves of 64 sorted edges -----------------
  {
    const int half = tid >> 8;
    const int c = tid & 255;
    const int i0 = half << 6, i1 = i0 + 64;
    const int fd = rowL[i0];
    float acc2 = 0.f;
    int prev = fd;
    for (int i = i0; i < i1; ++i) {
      int rr = rowL[i];
      if (rr != prev) {
        if (prev == fd) atomicAdd(&agg[(size_t)prev * 256 + c], acc2);
        else            agg[(size_t)prev * 256 + c] = acc2;   // interior: sole owner
        acc2 = 0.f; prev = rr;
      }
      acc2 += attL[i] * bf2f(A2[i * 264 + c]);
    }
    atomicAdd(&agg[(size_t)prev * 256 + c], acc2);
  }
}

// ---------------- node kernel: BM=64, staged A, barrier-light, nt hout ----------
__global__ __launch_bounds__(512, 4) void node_kernel(
    const float* __restrict__ h, const float* __restrict__ agg,
    const float* __restrict__ nmask,
    const unsigned short* __restrict__ Wn1T, const float* __restrict__ bn1,
    const unsigned short* __restrict__ Wn2T, const float* __restrict__ bn2,
    float* __restrict__ hout) {
  __shared__ unsigned short Abuf[64 * 40];      // 5120 B
  __shared__ unsigned short A2[64 * 264];       // 33792 B
  __shared__ float bn1L[256], bn2L[256];        // 2048 B

  const int tid = threadIdx.x;
  const int lane = tid & 63;
  const int wid = tid >> 6;
  const int n0 = blockIdx.x * 64;

  if (tid < 256) { bn1L[tid] = bn1[tid]; bn2L[tid] = bn2[tid]; }

  f32x4 acc[2][4];
  #pragma unroll
  for (int m = 0; m < 2; m++)
    #pragma unroll
    for (int n = 0; n < 4; n++) acc[m][n] = (f32x4){0.f, 0.f, 0.f, 0.f};

  const int wrr = wid >> 2, wcc = wid & 3;      // 2 x 4 wave grid, wrr covers 32 rows
  const int rbase = (wrr << 5) + (lane & 15);
  const int koff = (lane >> 4) << 3;
  const int cfrag = lane & 15;

  const int eA = tid >> 2, sA = tid & 3;        // eA 0..127 but only eA<64 used
  int nodeA = n0 + (eA & 63); if (nodeA >= NN) nodeA = NN - 1;

  for (int kt = 0; kt < 16; ++kt) {
    const int k0 = kt << 5;
    __syncthreads();
    if (eA < 64) {
      const float* src = (k0 < 256) ? (h + (size_t)nodeA * 256 + k0 + (sA << 3))
                                    : (agg + (size_t)nodeA * 256 + (k0 - 256) + (sA << 3));
      const float sc = (k0 < 256) ? 1.0f : (1.0f / 32.0f);
      float4 f0 = *(const float4*)src;
      float4 f1 = *(const float4*)(src + 4);
      s16x8 v;
      v[0] = (short)f2bf(f0.x * sc); v[1] = (short)f2bf(f0.y * sc);
      v[2] = (short)f2bf(f0.z * sc); v[3] = (short)f2bf(f0.w * sc);
      v[4] = (short)f2bf(f1.x * sc); v[5] = (short)f2bf(f1.y * sc);
      v[6] = (short)f2bf(f1.z * sc); v[7] = (short)f2bf(f1.w * sc);
      *(s16x8*)&Abuf[eA * 40 + (sA << 3)] = v;
    }
    __syncthreads();
    bf16x8 a[2], b[4];
    #pragma unroll
    for (int m = 0; m < 2; m++)
      a[m] = __builtin_bit_cast(bf16x8, *(const s16x8*)&Abuf[(rbase + m * 16) * 40 + koff]);
    #pragma unroll
    for (int n = 0; n < 4; n++)
      b[n] = __builtin_bit_cast(bf16x8,
               *(const s16x8*)(Wn1T + (((wcc << 6) + n * 16 + cfrag) << 9) + k0 + koff));
    #pragma unroll
    for (int m = 0; m < 2; m++)
      #pragma unroll
      for (int n = 0; n < 4; n++)
        acc[m][n] = __builtin_amdgcn_mfma_f32_16x16x32_bf16(a[m], b[n], acc[m][n], 0, 0, 0);
  }

  #pragma unroll
  for (int m = 0; m < 2; m++) {
    int rl = (wrr << 5) + m * 16 + ((lane >> 4) << 2);
    #pragma unroll
    for (int n = 0; n < 4; n++) {
      int cg = (wcc << 6) + n * 16 + cfrag;
      float bias = bn1L[cg];
      #pragma unroll
      for (int j = 0; j < 4; j++) {
        float x = acc[m][n][j] + bias;
        A2[(rl + j) * 264 + cg] = f2bf(silu_f(x));
      }
      acc[m][n] = (f32x4){0.f, 0.f, 0.f, 0.f};
    }
  }
  __syncthreads();  // hidden1 visible

  #pragma unroll
  for (int kt = 0; kt < 8; ++kt) {
    const int k0 = kt << 5;
    bf16x8 a[2], b[4];
    #pragma unroll
    for (int m = 0; m < 2; m++)
      a[m] = __builtin_bit_cast(bf16x8, *(const s16x8*)&A2[(rbase + m * 16) * 264 + k0 + koff]);
    #pragma unroll
    for (int n = 0; n < 4; n++)
      b[n] = __builtin_bit_cast(bf16x8,
               *(const s16x8*)(Wn2T + (((wcc << 6) + n * 16 + cfrag) << 8) + k0 + koff));
    #pragma unroll
    for (int m = 0; m < 2; m++)
      #pragma unroll
      for (int n = 0; n < 4; n++)
        acc[m][n] = __builtin_amdgcn_mfma_f32_16x16x32_bf16(a[m], b[n], acc[m][n], 0, 0, 0);
  }

  #pragma unroll
  for (int m = 0; m < 2; m++) {
    int rl = (wrr << 5) + m * 16 + ((lane >> 4) << 2);
    #pragma unroll
    for (int n = 0; n < 4; n++) {
      int cg = (wcc << 6) + n * 16 + cfrag;
      #pragma unroll
      for (int j = 0; j < 4; j++) {
        int rg = n0 + rl + j;
        if (rg < NN) {
          float val = acc[m][n][j] + bn2L[cg];
          float o = (h[(size_t)rg * 256 + cg] + val) * nmask[rg];
          __builtin_nontemporal_store(o, &hout[(size_t)rg * 256 + cg]);
        }
      }
    }
  }
}

extern "C" void kernel_launch(void* const* d_in, const int* in_sizes, int n_in,
                              void* d_out, int out_size, void* d_ws, size_t ws_size,
                              hipStream_t stream) {
  (void)in_sizes; (void)n_in; (void)out_size; (void)ws_size;
  const float* h     = (const float*)d_in[0];
  const int*   eidx  = (const int*)d_in[1];
  const float* eattr = (const float*)d_in[2];
  const float* nmask = (const float*)d_in[3];
  const float* emask = (const float*)d_in[4];
  const float* We1 = (const float*)d_in[5];
  const float* be1 = (const float*)d_in[6];
  const float* We2 = (const float*)d_in[7];
  const float* be2 = (const float*)d_in[8];
  const float* Wa  = (const float*)d_in[9];
  const float* ba  = (const float*)d_in[10];
  const float* Wn1 = (const float*)d_in[11];
  const float* bn1 = (const float*)d_in[12];
  const float* Wn2 = (const float*)d_in[13];
  const float* bn2 = (const float*)d_in[14];

  char* ws = (char*)d_ws;
  unsigned short* W1abT = (unsigned short*)(ws + 0);         // 262,144 B
  unsigned short* W1cT  = (unsigned short*)(ws + 262144);    // 16,384
  unsigned short* We2T  = (unsigned short*)(ws + 278528);    // 131,072
  unsigned short* Wn1T  = (unsigned short*)(ws + 409600);    // 262,144
  unsigned short* Wn2T  = (unsigned short*)(ws + 671744);    // 131,072
  unsigned short* hPQb  = (unsigned short*)(ws + 802816);    // 10,240,000
  float* agg      = (float*)(ws + 11042816);                 // 10,240,000
  int*   counts   = (int*)(ws + 21282816);                   // 40,000
  int*   rowStart = (int*)(ws + 21322816);                   // 40,008
  int*   cursor   = (int*)(ws + 21362824);                   // 40,000
  int*   eorder   = (int*)(ws + 21402824);                   // 1,280,000
  int*   rowi     = (int*)(ws + 22682824);                   // 1,280,000
  int*   rowSorted= (int*)(ws + 23962824);                   // 1,280,000
  unsigned short* hb = (unsigned short*)(ws + 25242824);     // 5,120,000 -> 30,362,824

  float* hout = (float*)d_out;
  float* mij  = (float*)d_out + (size_t)NN * 256;

  hipMemsetAsync(counts, 0, NN * sizeof(int), stream);
  hipMemsetAsync(agg, 0, (size_t)NN * 256 * sizeof(float), stream);
  prep_all<<<2659, 512, 0, stream>>>(We1, We2, Wn1, Wn2, h, eidx,
                                     W1abT, W1cT, We2T, Wn1T, Wn2T, hb, rowi, counts);
  scan_kernel<<<1, 1024, 0, stream>>>(counts, rowStart, cursor);
  hpq_scatter<<<783, 512, 0, stream>>>(hb, W1abT, hPQb, rowi, cursor, eorder, rowSorted);
  edge_kernel<<<NE / 128, 512, 0, stream>>>(hPQb, eidx, eattr, emask, W1cT, be1, We2T, be2,
                                            Wa, ba, eorder, rowSorted, mij, agg);
  node_kernel<<<(NN + 63) / 64, 512, 0, stream>>>(h, agg, nmask, Wn1T, bn1, Wn2T, bn2, hout);
}